// Round 12
// baseline (568.077 us; speedup 1.0000x reference)
//
#include <hip/hip_runtime.h>
#include <hip/hip_bf16.h>
#include <stdint.h>

#define DEVI __device__ __forceinline__

typedef __attribute__((ext_vector_type(8))) short bf16x8;
typedef __attribute__((ext_vector_type(4))) float f32x4;
typedef __attribute__((ext_vector_type(4))) unsigned u32x4;

static DEVI unsigned short f2bf(float f) {
  unsigned int u = __builtin_bit_cast(unsigned int, f);
  u = (u + 0x7FFFu + ((u >> 16) & 1u)) >> 16;
  return (unsigned short)u;
}

static DEVI void async16(const void* g, void* l) {
  __builtin_amdgcn_global_load_lds((__attribute__((address_space(1))) void*)(g),
                                   (__attribute__((address_space(3))) void*)(l),
                                   16, 0, 0);
}

// ---------------- f32 -> bf16 convert ----------------
__global__ __launch_bounds__(256) void cvt_kernel(const float* __restrict__ in,
                                                  unsigned short* __restrict__ out, int n4) {
  int i = blockIdx.x * 256 + threadIdx.x;
  if (i >= n4) return;
  float4 v = ((const float4*)in)[i];
  uint2 o;
  o.x = (unsigned)f2bf(v.x) | ((unsigned)f2bf(v.y) << 16);
  o.y = (unsigned)f2bf(v.z) | ((unsigned)f2bf(v.w) << 16);
  ((uint2*)out)[i] = o;
}

// ---- mask int32 -> 1 bit per element (word w covers cols [w*64, w*64+64)) ----
__global__ __launch_bounds__(256) void maskbits_kernel(const int* __restrict__ mask,
                                                       unsigned long long* __restrict__ mb) {
  size_t tg = (size_t)blockIdx.x * 256 + threadIdx.x;
  int v = mask[tg];
  unsigned long long bal = __ballot(v != 0);
  if ((threadIdx.x & 63) == 0) mb[tg >> 6] = bal;
}

// ---- W [1024 in][1024 out] f32 -> Wt [out][in] bf16 (transpose + convert + scale) ----
__global__ __launch_bounds__(256) void wtrans_kernel(const float* __restrict__ W,
                                                     unsigned short* __restrict__ Wt,
                                                     float scale) {
  __shared__ float t[32][33];
  const int bx = blockIdx.x * 32;  // out (n)
  const int by = blockIdx.y * 32;  // in (k)
  const int tx = threadIdx.x, ty = threadIdx.y;  // 32 x 8
#pragma unroll
  for (int i = 0; i < 32; i += 8) t[ty + i][tx] = W[(size_t)(by + ty + i) * 1024 + bx + tx];
  __syncthreads();
#pragma unroll
  for (int i = 0; i < 32; i += 8)
    Wt[(size_t)(bx + ty + i) * 1024 + by + tx] = f2bf(t[tx][ty + i] * scale);
}

// ---------------- NT GEMM: C[M,N] = A[M,K] * B[N,K]^T, bf16 in, bf16/f32 out --------
// 128x128 tile, BK=64, 4 waves, 16x16x32 MFMA (m97 structure).
// T1 XCD remap: 1D grid 512, xcd=g&7 owns a contiguous 8-M-tile band x all 8 N-tiles
// -> per-XCD working set = 2MB A-band + 2MB B, L2-resident.
template <bool OUT_F32>
__global__ __launch_bounds__(256) void gemm_nt(const unsigned short* __restrict__ A, int lda,
                                               const unsigned short* __restrict__ B, int ldb,
                                               void* __restrict__ Cp, int ldc, int K) {
  __shared__ unsigned short As[128 * 64];
  __shared__ unsigned short Bs[128 * 64];
  const int tid = threadIdx.x;
  const int wave = tid >> 6, lane = tid & 63;
  const int g = blockIdx.x;
  const int xcd = g & 7, i4 = g >> 3;
  const int m0 = (xcd * 8 + (i4 >> 3)) * 128;
  const int n0 = (i4 & 7) * 128;
  const int wr = (wave >> 1) * 64, wc = (wave & 1) * 64;
  const int fr = lane & 15, fg = lane >> 4;
  f32x4 acc[4][4] = {};
  for (int kt = 0; kt < K; kt += 64) {
    __syncthreads();
#pragma unroll
    for (int it = 0; it < 4; ++it) {
      int id = it * 256 + tid;
      int row = id >> 3, ch = id & 7;
      async16(A + (size_t)(m0 + row) * lda + kt + ch * 8,
              (char*)As + (it * 256 + wave * 64) * 16);
      async16(B + (size_t)(n0 + row) * ldb + kt + ch * 8,
              (char*)Bs + (it * 256 + wave * 64) * 16);
    }
    __syncthreads();
#pragma unroll
    for (int ks = 0; ks < 2; ++ks) {
      bf16x8 af[4], bfr[4];
#pragma unroll
      for (int i = 0; i < 4; ++i)
        af[i] = *(const bf16x8*)(As + (wr + i * 16 + fr) * 64 + ks * 32 + fg * 8);
#pragma unroll
      for (int j = 0; j < 4; ++j)
        bfr[j] = *(const bf16x8*)(Bs + (wc + j * 16 + fr) * 64 + ks * 32 + fg * 8);
#pragma unroll
      for (int i = 0; i < 4; ++i)
#pragma unroll
        for (int j = 0; j < 4; ++j)
          acc[i][j] = __builtin_amdgcn_mfma_f32_16x16x32_bf16(af[i], bfr[j], acc[i][j], 0, 0, 0);
    }
  }
#pragma unroll
  for (int i = 0; i < 4; ++i)
#pragma unroll
    for (int j = 0; j < 4; ++j)
#pragma unroll
      for (int r = 0; r < 4; ++r) {
        int row = m0 + wr + i * 16 + fg * 4 + r;
        int col = n0 + wc + j * 16 + fr;
        if (OUT_F32)
          ((float*)Cp)[(size_t)row * ldc + col] = acc[i][j][r];
        else
          ((unsigned short*)Cp)[(size_t)row * ldc + col] = f2bf(acc[i][j][r]);
      }
}

// ---- Vp [b*2048+l][h*64+d] bf16 -> Vt [bh][d][l] bf16 (per-head transpose) ----
__global__ __launch_bounds__(256) void vtrans_kernel(const unsigned short* __restrict__ Vp,
                                                     unsigned short* __restrict__ Vt) {
  __shared__ unsigned short t[64][72];
  const int bh = blockIdx.y;
  const int b = bh >> 4, h = bh & 15;
  const int l0 = blockIdx.x * 64;
  const int tid = threadIdx.x;
#pragma unroll
  for (int it = 0; it < 2; ++it) {
    int id = it * 256 + tid;
    int l = id >> 3, ch = id & 7;
    uint4 v = *(const uint4*)(Vp + (size_t)(b * 2048 + l0 + l) * 1024 + h * 64 + ch * 8);
    *(uint4*)(&t[l][ch * 8]) = v;
  }
  __syncthreads();
#pragma unroll
  for (int it = 0; it < 2; ++it) {
    int id = it * 256 + tid;
    int d = id >> 3, lc = id & 7;
    unsigned short o[8];
#pragma unroll
    for (int k = 0; k < 8; ++k) o[k] = t[lc * 8 + k][d];
    uint4 ov;
    ov.x = o[0] | ((unsigned)o[1] << 16);
    ov.y = o[2] | ((unsigned)o[3] << 16);
    ov.z = o[4] | ((unsigned)o[5] << 16);
    ov.w = o[6] | ((unsigned)o[7] << 16);
    *(uint4*)(Vt + ((size_t)bh * 64 + d) * 2048 + l0 + lc * 8) = ov;
  }
}

// ------ fused attention (r11 chassis + paired-tile pass 1, unioned LDS) ------
// grid 1024 = 8 XCD x 8 bh x 16 q-tiles, 512 threads (8 waves x 16 q-rows).
// Pass 1: KVBLK=128 (two 64-k tiles per staged buffer) -> iterations 32->16,
// barriers halved. Peeled last iteration (no wrap stage: it would race the
// pass-2 prologue restage into the unioned LDS). FIFO: steady vmcnt(3)
// (1 mask-pair + 2 stage entries newer than awaited pair), peel vmcnt(1).
// Pass 2: unchanged r11 (coalesced LDS-bounced attn stores), explicit K0/V0
// prologue, steady vmcnt(7).
// LDS union (66048B): pass1 Kpair[2][16384] @0 | pass2 Ks2[2][8192] @0,
// Vs2[2][8192] @16384, Os f32[8][1040] @32768.
__global__ __launch_bounds__(512, 4) void attn_kernel(
    const unsigned short* __restrict__ Qp, const unsigned short* __restrict__ Kp,
    const unsigned short* __restrict__ Vt, const unsigned long long* __restrict__ mb,
    float* __restrict__ attn_out, unsigned short* __restrict__ ctx) {
  __shared__ __align__(16) char smem[66048];
  const int tid = threadIdx.x, wave = tid >> 6, lane = tid & 63;
  const int g = blockIdx.x;
  const int idx = g >> 3;
  const int bh = (g & 7) * 8 + (idx >> 4);  // same-XCD blocks share 8 heads
  const int b = bh >> 4, h = bh & 15;
  const int q0 = (idx & 15) * 128;
  const int fr = lane & 15, fg = lane >> 4;
  const int q = q0 + wave * 16 + fr;  // this lane's q row

  // ---- staging coords: thread covers row r0 (of 64), chunk pre-swizzled ----
  const int r0 = tid >> 3;
  const int chs = ((tid & 7) ^ (r0 & 7)) << 3;  // swizzled u16 chunk offset
  const unsigned short* kg = Kp + (size_t)(b * 2048 + r0) * 1024 + h * 64 + chs;
  const unsigned short* vg = Vt + (size_t)bh * 131072 + (size_t)r0 * 2048 + chs;

#define STAGE_P1(buf, pair)                                                 \
  do {                                                                      \
    const unsigned short* _k = kg + (size_t)(pair) * 131072;                \
    async16(_k, smem + (buf) * 16384 + wave * 1024);                        \
    async16(_k + 65536, smem + (buf) * 16384 + 8192 + wave * 1024);         \
  } while (0)
#define STAGE_K2(buf, t) async16(kg + (size_t)(t) * 65536, smem + (buf) * 8192 + wave * 1024)
#define STAGE_V2(buf, t) async16(vg + (t) * 64, smem + 16384 + (buf) * 8192 + wave * 1024)

  // ---- fragment read offsets (swizzle involution on chunk) ----
  const int c0 = (fg ^ (fr & 7)) << 3;        // ks=0 chunk
  const int c1 = ((4 + fg) ^ (fr & 7)) << 3;  // ks=1 chunk

  // Q fragment (B-operand), scale pre-folded into W_Q
  const unsigned short* qbase = Qp + (size_t)(b * 2048 + q) * 1024 + h * 64 + fg * 8;
  bf16x8 qa0 = *(const bf16x8*)(qbase);
  bf16x8 qa1 = *(const bf16x8*)(qbase + 32);

  const unsigned long long* mrow = mb + (size_t)(b * 2048 + q) * 32;
  const int msh = fg * 4;
  const float ninf = __uint_as_float(0xFF800000u);

#define P1_TILE(Kbase, mw)                                                       \
  {                                                                              \
    f32x4 s[4] = {};                                                             \
    _Pragma("unroll") for (int j = 0; j < 4; ++j) {                              \
      bf16x8 k0 = *(const bf16x8*)((Kbase) + (j * 16 + fr) * 64 + c0);           \
      bf16x8 k1 = *(const bf16x8*)((Kbase) + (j * 16 + fr) * 64 + c1);           \
      s[j] = __builtin_amdgcn_mfma_f32_16x16x32_bf16(k0, qa0, s[j], 0, 0, 0);    \
      s[j] = __builtin_amdgcn_mfma_f32_16x16x32_bf16(k1, qa1, s[j], 0, 0, 0);    \
    }                                                                            \
    unsigned mlo = (unsigned)(mw), mhi = (unsigned)((mw) >> 32);                 \
    _Pragma("unroll") for (int j = 0; j < 4; ++j) {                              \
      unsigned mj = ((j & 2) ? mhi : mlo) >> ((j & 1) * 16 + msh);               \
      _Pragma("unroll") for (int r = 0; r < 4; ++r)                              \
          rsum += exp2f((mj & (1u << r)) ? ninf : s[j][r]);                      \
    }                                                                            \
  }

  // ================= pass 1: row sums of exp2(S), paired tiles =================
  STAGE_P1(0, 0);
  float rsum = 0.f;
  int buf = 0;
  for (int kt2 = 0; kt2 < 15; ++kt2) {
    ulonglong2 mp = *(const ulonglong2*)(mrow + 2 * kt2);
    STAGE_P1(buf ^ 1, kt2 + 1);
    asm volatile("s_waitcnt vmcnt(3)" ::: "memory");  // pair kt2 landed
    __builtin_amdgcn_s_barrier();
    const unsigned short* Ka = (const unsigned short*)(smem + buf * 16384);
    P1_TILE(Ka, mp.x)
    P1_TILE(Ka + 4096, mp.y)
    asm volatile("s_waitcnt lgkmcnt(0)" ::: "memory");
    __builtin_amdgcn_s_barrier();
    buf ^= 1;
  }
  {  // peeled last pair (no wrap stage -> vmcnt(1))
    ulonglong2 mp = *(const ulonglong2*)(mrow + 30);
    asm volatile("s_waitcnt vmcnt(1)" ::: "memory");
    __builtin_amdgcn_s_barrier();
    const unsigned short* Ka = (const unsigned short*)(smem + buf * 16384);
    P1_TILE(Ka, mp.x)
    P1_TILE(Ka + 4096, mp.y)
    asm volatile("s_waitcnt lgkmcnt(0)" ::: "memory");
    __builtin_amdgcn_s_barrier();
  }
  rsum += __shfl_xor(rsum, 16);
  rsum += __shfl_xor(rsum, 32);
  const float rs = 1.0f / rsum;

  // ================= pass 2: normalize, write attn (coalesced), PV =================
  STAGE_K2(0, 0);
  STAGE_V2(0, 0);
  asm volatile("s_waitcnt vmcnt(0)" ::: "memory");  // one-time drain: K0 + V0
  __builtin_amdgcn_s_barrier();
  f32x4 o[4] = {};
  const int orow = lane >> 4, ocol = (lane & 15) * 4;
  float* abase = attn_out + ((size_t)bh * 2048 + q0 + wave * 16) * 2048;
  float* Osw = (float*)(smem + 32768) + wave * 1040;
  int cur = 0;

  for (int kt = 0; kt < 32; ++kt) {
    unsigned long long mw = mrow[kt];
    STAGE_K2(cur ^ 1, (kt + 1) & 31);
    STAGE_V2(cur ^ 1, (kt + 1) & 31);
    asm volatile("s_waitcnt vmcnt(7)" ::: "memory");  // tile-kt K+V landed
    __builtin_amdgcn_s_barrier();
    const unsigned short* Kc = (const unsigned short*)(smem + cur * 8192);
    const unsigned short* Vc = (const unsigned short*)(smem + 16384 + cur * 8192);
    f32x4 s[4] = {};
#pragma unroll
    for (int j = 0; j < 4; ++j) {
      bf16x8 k0 = *(const bf16x8*)(Kc + (j * 16 + fr) * 64 + c0);
      bf16x8 k1 = *(const bf16x8*)(Kc + (j * 16 + fr) * 64 + c1);
      s[j] = __builtin_amdgcn_mfma_f32_16x16x32_bf16(k0, qa0, s[j], 0, 0, 0);
      s[j] = __builtin_amdgcn_mfma_f32_16x16x32_bf16(k1, qa1, s[j], 0, 0, 0);
    }
    unsigned mlo = (unsigned)mw, mhi = (unsigned)(mw >> 32);
    unsigned pk[4][2];
#pragma unroll
    for (int j = 0; j < 4; ++j) {
      unsigned mj = ((j & 2) ? mhi : mlo) >> ((j & 1) * 16 + msh);
      float e0 = exp2f((mj & 1u) ? ninf : s[j][0]) * rs;
      float e1 = exp2f((mj & 2u) ? ninf : s[j][1]) * rs;
      float e2 = exp2f((mj & 4u) ? ninf : s[j][2]) * rs;
      float e3 = exp2f((mj & 8u) ? ninf : s[j][3]) * rs;
      f32x4 ev;
      ev[0] = e0; ev[1] = e1; ev[2] = e2; ev[3] = e3;
      *(f32x4*)(&Osw[fr * 65 + j * 16 + fg * 4]) = ev;  // LDS bounce
      asm("v_cvt_pk_bf16_f32 %0, %1, %2" : "=v"(pk[j][0]) : "v"(e0), "v"(e1));
      asm("v_cvt_pk_bf16_f32 %0, %1, %2" : "=v"(pk[j][1]) : "v"(e2), "v"(e3));
    }
    // in-register P redistribution (verified round 8): swap32 then swap16 of
    // (w[2ks][p], w[2ks+1][p]) yields the two A-operand words directly.
    unsigned x0 = pk[0][0], y0 = pk[1][0], x1 = pk[0][1], y1 = pk[1][1];
    unsigned x2 = pk[2][0], y2 = pk[3][0], x3 = pk[2][1], y3 = pk[3][1];
    asm("v_permlane32_swap_b32 %0, %1" : "+v"(x0), "+v"(y0));
    asm("v_permlane16_swap_b32 %0, %1" : "+v"(x0), "+v"(y0));
    asm("v_permlane32_swap_b32 %0, %1" : "+v"(x1), "+v"(y1));
    asm("v_permlane16_swap_b32 %0, %1" : "+v"(x1), "+v"(y1));
    asm("v_permlane32_swap_b32 %0, %1" : "+v"(x2), "+v"(y2));
    asm("v_permlane16_swap_b32 %0, %1" : "+v"(x2), "+v"(y2));
    asm("v_permlane32_swap_b32 %0, %1" : "+v"(x3), "+v"(y3));
    asm("v_permlane16_swap_b32 %0, %1" : "+v"(x3), "+v"(y3));
    u32x4 t0, t1;
    t0[0] = x0; t0[1] = x1; t0[2] = y0; t0[3] = y1;
    t1[0] = x2; t1[1] = x3; t1[2] = y2; t1[3] = y3;
    bf16x8 pa0 = __builtin_bit_cast(bf16x8, t0);
    bf16x8 pa1 = __builtin_bit_cast(bf16x8, t1);
#pragma unroll
    for (int ct = 0; ct < 4; ++ct) {
      bf16x8 v0 = *(const bf16x8*)(Vc + (ct * 16 + fr) * 64 + c0);
      bf16x8 v1 = *(const bf16x8*)(Vc + (ct * 16 + fr) * 64 + c1);
      o[ct] = __builtin_amdgcn_mfma_f32_16x16x32_bf16(pa0, v0, o[ct], 0, 0, 0);
      o[ct] = __builtin_amdgcn_mfma_f32_16x16x32_bf16(pa1, v1, o[ct], 0, 0, 0);
    }
    // coalesced write-out: instr i writes rows {orow+4i}, lanes 0-15 = one full
    // 256B row segment
#pragma unroll
    for (int i = 0; i < 4; ++i) {
      f32x4 ov = *(const f32x4*)(&Osw[(orow + 4 * i) * 65 + ocol]);
      __builtin_nontemporal_store(
          ov, (f32x4*)(abase + (size_t)(orow + 4 * i) * 2048 + kt * 64 + ocol));
    }
    asm volatile("s_waitcnt lgkmcnt(0)" ::: "memory");
    __builtin_amdgcn_s_barrier();
    cur ^= 1;
  }
#pragma unroll
  for (int ct = 0; ct < 4; ++ct)
#pragma unroll
    for (int r = 0; r < 4; ++r)
      ctx[(size_t)(b * 2048 + q0 + wave * 16 + fg * 4 + r) * 1024 + h * 64 + ct * 16 + fr] =
          f2bf(o[ct][r]);
#undef STAGE_P1
#undef STAGE_K2
#undef STAGE_V2
#undef P1_TILE
}

// ---------------- fused residual-add + LayerNorm ----------------
__global__ __launch_bounds__(256) void ln_kernel(const float* __restrict__ resl,
                                                 const float* __restrict__ inQ,
                                                 float* __restrict__ out) {
  __shared__ float red[8];
  const int row = blockIdx.x, tid = threadIdx.x;
  const int wave = tid >> 6, lane = tid & 63;
  float4 xv = ((const float4*)(resl + (size_t)row * 1024))[tid];
  float4 qv = ((const float4*)(inQ + (size_t)row * 1024))[tid];
  float v0 = xv.x + qv.x, v1 = xv.y + qv.y, v2 = xv.z + qv.z, v3 = xv.w + qv.w;
  float s = v0 + v1 + v2 + v3;
  float s2 = v0 * v0 + v1 * v1 + v2 * v2 + v3 * v3;
#pragma unroll
  for (int off = 1; off < 64; off <<= 1) {
    s += __shfl_xor(s, off);
    s2 += __shfl_xor(s2, off);
  }
  if (lane == 0) { red[wave] = s; red[4 + wave] = s2; }
  __syncthreads();
  s = red[0] + red[1] + red[2] + red[3];
  s2 = red[4] + red[5] + red[6] + red[7];
  const float mu = s * (1.0f / 1024.0f);
  const float var = s2 * (1.0f / 1024.0f) - mu * mu;
  const float inv = rsqrtf(var + 1e-5f);
  float4 ov;
  ov.x = (v0 - mu) * inv;
  ov.y = (v1 - mu) * inv;
  ov.z = (v2 - mu) * inv;
  ov.w = (v3 - mu) * inv;
  ((float4*)(out + (size_t)row * 1024))[tid] = ov;
}

extern "C" void kernel_launch(void* const* d_in, const int* in_sizes, int n_in, void* d_out,
                              int out_size, void* d_ws, size_t ws_size, hipStream_t stream) {
  const float* inQ = (const float*)d_in[0];
  const float* inK = (const float*)d_in[1];
  const float* inV = (const float*)d_in[2];
  const int* mask = (const int*)d_in[3];
  const float* WQ = (const float*)d_in[4];
  const float* WK = (const float*)d_in[5];
  const float* WV = (const float*)d_in[6];
  const float* WF = (const float*)d_in[7];
  float* res = (float*)d_out;
  float* attn = res + (size_t)8192 * 1024;

  char* w = (char*)d_ws;
  unsigned short* inQb = (unsigned short*)w; w += (size_t)16777216;
  unsigned short* inKb = (unsigned short*)w; w += (size_t)16777216;
  unsigned short* inVb = (unsigned short*)w; w += (size_t)16777216;
  unsigned short* WQt = (unsigned short*)w; w += (size_t)2097152;
  unsigned short* WKt = (unsigned short*)w; w += (size_t)2097152;
  unsigned short* WVt = (unsigned short*)w; w += (size_t)2097152;
  unsigned short* WFt = (unsigned short*)w; w += (size_t)2097152;
  unsigned short* Qp  = (unsigned short*)w; w += (size_t)16777216;
  unsigned short* Kp  = (unsigned short*)w; w += (size_t)16777216;
  unsigned short* Vp  = (unsigned short*)w; w += (size_t)16777216;
  unsigned short* Vtb = (unsigned short*)w; w += (size_t)16777216;
  unsigned short* ctx = (unsigned short*)w; w += (size_t)16777216;
  float* resl = (float*)w; w += (size_t)33554432;
  // mask bitwords reuse inQb's space (dead after the Q projection GEMM)
  unsigned long long* mbits = (unsigned long long*)inQb;

  cvt_kernel<<<8192, 256, 0, stream>>>(inQ, inQb, 2097152);
  cvt_kernel<<<8192, 256, 0, stream>>>(inK, inKb, 2097152);
  cvt_kernel<<<8192, 256, 0, stream>>>(inV, inVb, 2097152);
  dim3 wb(32, 8);
  // fold 1/sqrt(64) * log2(e) into W_Q so attn uses exp2(S) directly
  wtrans_kernel<<<dim3(32, 32), wb, 0, stream>>>(WQ, WQt, 0.18033688f);
  wtrans_kernel<<<dim3(32, 32), wb, 0, stream>>>(WK, WKt, 1.0f);
  wtrans_kernel<<<dim3(32, 32), wb, 0, stream>>>(WV, WVt, 1.0f);
  wtrans_kernel<<<dim3(32, 32), wb, 0, stream>>>(WF, WFt, 1.0f);
  gemm_nt<false><<<512, 256, 0, stream>>>(inQb, 1024, WQt, 1024, Qp, 1024, 1024);
  gemm_nt<false><<<512, 256, 0, stream>>>(inKb, 1024, WKt, 1024, Kp, 1024, 1024);
  gemm_nt<false><<<512, 256, 0, stream>>>(inVb, 1024, WVt, 1024, Vp, 1024, 1024);
  maskbits_kernel<<<65536, 256, 0, stream>>>(mask, mbits);
  vtrans_kernel<<<dim3(32, 64), 256, 0, stream>>>(Vp, Vtb);
  attn_kernel<<<1024, 512, 0, stream>>>(Qp, Kp, Vtb, mbits, attn, ctx);
  gemm_nt<true><<<512, 256, 0, stream>>>(ctx, 1024, WFt, 1024, resl, 1024, 1024);
  ln_kernel<<<8192, 256, 0, stream>>>(resl, inQ, res);
}

// Round 13
// 489.721 us; speedup vs baseline: 1.1600x; 1.1600x over previous
//
#include <hip/hip_runtime.h>
#include <hip/hip_bf16.h>
#include <stdint.h>

#define DEVI __device__ __forceinline__

typedef __attribute__((ext_vector_type(8))) short bf16x8;
typedef __attribute__((ext_vector_type(4))) float f32x4;
typedef __attribute__((ext_vector_type(4))) unsigned u32x4;

static DEVI unsigned short f2bf(float f) {
  unsigned int u = __builtin_bit_cast(unsigned int, f);
  u = (u + 0x7FFFu + ((u >> 16) & 1u)) >> 16;
  return (unsigned short)u;
}

static DEVI void async16(const void* g, void* l) {
  __builtin_amdgcn_global_load_lds((__attribute__((address_space(1))) void*)(g),
                                   (__attribute__((address_space(3))) void*)(l),
                                   16, 0, 0);
}

// ---------------- f32 -> bf16 convert ----------------
__global__ __launch_bounds__(256) void cvt_kernel(const float* __restrict__ in,
                                                  unsigned short* __restrict__ out, int n4) {
  int i = blockIdx.x * 256 + threadIdx.x;
  if (i >= n4) return;
  float4 v = ((const float4*)in)[i];
  uint2 o;
  o.x = (unsigned)f2bf(v.x) | ((unsigned)f2bf(v.y) << 16);
  o.y = (unsigned)f2bf(v.z) | ((unsigned)f2bf(v.w) << 16);
  ((uint2*)out)[i] = o;
}

// ---- mask int32 -> 1 bit per element (word w covers cols [w*64, w*64+64)) ----
__global__ __launch_bounds__(256) void maskbits_kernel(const int* __restrict__ mask,
                                                       unsigned long long* __restrict__ mb) {
  size_t tg = (size_t)blockIdx.x * 256 + threadIdx.x;
  int v = mask[tg];
  unsigned long long bal = __ballot(v != 0);
  if ((threadIdx.x & 63) == 0) mb[tg >> 6] = bal;
}

// ---- W [1024 in][1024 out] f32 -> Wt [out][in] bf16 (transpose + convert + scale) ----
__global__ __launch_bounds__(256) void wtrans_kernel(const float* __restrict__ W,
                                                     unsigned short* __restrict__ Wt,
                                                     float scale) {
  __shared__ float t[32][33];
  const int bx = blockIdx.x * 32;  // out (n)
  const int by = blockIdx.y * 32;  // in (k)
  const int tx = threadIdx.x, ty = threadIdx.y;  // 32 x 8
#pragma unroll
  for (int i = 0; i < 32; i += 8) t[ty + i][tx] = W[(size_t)(by + ty + i) * 1024 + bx + tx];
  __syncthreads();
#pragma unroll
  for (int i = 0; i < 32; i += 8)
    Wt[(size_t)(bx + ty + i) * 1024 + by + tx] = f2bf(t[tx][ty + i] * scale);
}

// ---------------- NT GEMM: C[M,N] = A[M,K] * B[N,K]^T, bf16 in, bf16/f32 out --------
// 128x128 tile, BK=64, 4 waves, 16x16x32 MFMA (m97 structure).
// T1 XCD remap: 1D grid 512, xcd=g&7 owns a contiguous 8-M-tile band x all 8 N-tiles
// -> per-XCD working set = 2MB A-band + 2MB B, L2-resident.  [A/B: suspect #2 of r12]
template <bool OUT_F32>
__global__ __launch_bounds__(256) void gemm_nt(const unsigned short* __restrict__ A, int lda,
                                               const unsigned short* __restrict__ B, int ldb,
                                               void* __restrict__ Cp, int ldc, int K) {
  __shared__ unsigned short As[128 * 64];
  __shared__ unsigned short Bs[128 * 64];
  const int tid = threadIdx.x;
  const int wave = tid >> 6, lane = tid & 63;
  const int g = blockIdx.x;
  const int xcd = g & 7, i4 = g >> 3;
  const int m0 = (xcd * 8 + (i4 >> 3)) * 128;
  const int n0 = (i4 & 7) * 128;
  const int wr = (wave >> 1) * 64, wc = (wave & 1) * 64;
  const int fr = lane & 15, fg = lane >> 4;
  f32x4 acc[4][4] = {};
  for (int kt = 0; kt < K; kt += 64) {
    __syncthreads();
#pragma unroll
    for (int it = 0; it < 4; ++it) {
      int id = it * 256 + tid;
      int row = id >> 3, ch = id & 7;
      async16(A + (size_t)(m0 + row) * lda + kt + ch * 8,
              (char*)As + (it * 256 + wave * 64) * 16);
      async16(B + (size_t)(n0 + row) * ldb + kt + ch * 8,
              (char*)Bs + (it * 256 + wave * 64) * 16);
    }
    __syncthreads();
#pragma unroll
    for (int ks = 0; ks < 2; ++ks) {
      bf16x8 af[4], bfr[4];
#pragma unroll
      for (int i = 0; i < 4; ++i)
        af[i] = *(const bf16x8*)(As + (wr + i * 16 + fr) * 64 + ks * 32 + fg * 8);
#pragma unroll
      for (int j = 0; j < 4; ++j)
        bfr[j] = *(const bf16x8*)(Bs + (wc + j * 16 + fr) * 64 + ks * 32 + fg * 8);
#pragma unroll
      for (int i = 0; i < 4; ++i)
#pragma unroll
        for (int j = 0; j < 4; ++j)
          acc[i][j] = __builtin_amdgcn_mfma_f32_16x16x32_bf16(af[i], bfr[j], acc[i][j], 0, 0, 0);
    }
  }
#pragma unroll
  for (int i = 0; i < 4; ++i)
#pragma unroll
    for (int j = 0; j < 4; ++j)
#pragma unroll
      for (int r = 0; r < 4; ++r) {
        int row = m0 + wr + i * 16 + fg * 4 + r;
        int col = n0 + wc + j * 16 + fr;
        if (OUT_F32)
          ((float*)Cp)[(size_t)row * ldc + col] = acc[i][j][r];
        else
          ((unsigned short*)Cp)[(size_t)row * ldc + col] = f2bf(acc[i][j][r]);
      }
}

// ---- Vp [b*2048+l][h*64+d] bf16 -> Vt [bh][d][l] bf16 (per-head transpose) ----
__global__ __launch_bounds__(256) void vtrans_kernel(const unsigned short* __restrict__ Vp,
                                                     unsigned short* __restrict__ Vt) {
  __shared__ unsigned short t[64][72];
  const int bh = blockIdx.y;
  const int b = bh >> 4, h = bh & 15;
  const int l0 = blockIdx.x * 64;
  const int tid = threadIdx.x;
#pragma unroll
  for (int it = 0; it < 2; ++it) {
    int id = it * 256 + tid;
    int l = id >> 3, ch = id & 7;
    uint4 v = *(const uint4*)(Vp + (size_t)(b * 2048 + l0 + l) * 1024 + h * 64 + ch * 8);
    *(uint4*)(&t[l][ch * 8]) = v;
  }
  __syncthreads();
#pragma unroll
  for (int it = 0; it < 2; ++it) {
    int id = it * 256 + tid;
    int d = id >> 3, lc = id & 7;
    unsigned short o[8];
#pragma unroll
    for (int k = 0; k < 8; ++k) o[k] = t[lc * 8 + k][d];
    uint4 ov;
    ov.x = o[0] | ((unsigned)o[1] << 16);
    ov.y = o[2] | ((unsigned)o[3] << 16);
    ov.z = o[4] | ((unsigned)o[5] << 16);
    ov.w = o[6] | ((unsigned)o[7] << 16);
    *(uint4*)(Vt + ((size_t)bh * 64 + d) * 2048 + l0 + lc * 8) = ov;
  }
}

// ------ fused attention (round-11 kernel VERBATIM — best known, 485 us) ------
// grid 1024 = 8 XCD x 8 bh x 16 q-tiles, 512 threads (8 waves x 16 q-rows).
// LDS-bounced coalesced attn stores ([16][65] f32 bounce -> 4x256B contiguous
// segments per instr). FIFO waits: pass1 vmcnt(2), pass2 vmcnt(7).
__global__ __launch_bounds__(512, 4) void attn_kernel(
    const unsigned short* __restrict__ Qp, const unsigned short* __restrict__ Kp,
    const unsigned short* __restrict__ Vt, const unsigned long long* __restrict__ mb,
    float* __restrict__ attn_out, unsigned short* __restrict__ ctx) {
  __shared__ unsigned short Ks[2][4096];
  __shared__ unsigned short Vs[2][4096];
  __shared__ float Os[8][16 * 65];
  const int tid = threadIdx.x, wave = tid >> 6, lane = tid & 63;
  const int g = blockIdx.x;
  const int idx = g >> 3;
  const int bh = (g & 7) * 8 + (idx >> 4);  // same-XCD blocks share 8 heads
  const int b = bh >> 4, h = bh & 15;
  const int q0 = (idx & 15) * 128;
  const int fr = lane & 15, fg = lane >> 4;
  const int q = q0 + wave * 16 + fr;  // this lane's q row

  // ---- staging coords: thread covers row r0 (of 64), chunk pre-swizzled ----
  const int r0 = tid >> 3;
  const int chs = ((tid & 7) ^ (r0 & 7)) << 3;  // swizzled u16 chunk offset
  const unsigned short* kg = Kp + (size_t)(b * 2048 + r0) * 1024 + h * 64 + chs;
  const unsigned short* vg = Vt + (size_t)bh * 131072 + (size_t)r0 * 2048 + chs;

#define STAGE_K(buf, t) async16(kg + (size_t)(t) * 65536, (char*)Ks[buf] + wave * 1024)
#define STAGE_V(buf, t) async16(vg + (t) * 64, (char*)Vs[buf] + wave * 1024)

  // ---- fragment read offsets (swizzle involution on chunk) ----
  const int c0 = (fg ^ (fr & 7)) << 3;        // ks=0 chunk
  const int c1 = ((4 + fg) ^ (fr & 7)) << 3;  // ks=1 chunk

  // Q fragment (B-operand), scale pre-folded into W_Q
  const unsigned short* qbase = Qp + (size_t)(b * 2048 + q) * 1024 + h * 64 + fg * 8;
  bf16x8 qa0 = *(const bf16x8*)(qbase);
  bf16x8 qa1 = *(const bf16x8*)(qbase + 32);

  const unsigned long long* mrow = mb + (size_t)(b * 2048 + q) * 32;
  const int msh = fg * 4;
  const float ninf = __uint_as_float(0xFF800000u);

  // ================= pass 1: row sums of exp2(S) =================
  STAGE_K(0, 0);
  int cur = 0;
  float rsum = 0.f;
  for (int kt = 0; kt < 32; ++kt) {
    unsigned long long mw = mrow[kt];
    STAGE_K(cur ^ 1, (kt + 1) & 31);
    asm volatile("s_waitcnt vmcnt(2)" ::: "memory");  // tile-kt K retired
    __builtin_amdgcn_s_barrier();
    f32x4 s[4] = {};
#pragma unroll
    for (int j = 0; j < 4; ++j) {
      bf16x8 k0 = *(const bf16x8*)(&Ks[cur][(j * 16 + fr) * 64 + c0]);
      bf16x8 k1 = *(const bf16x8*)(&Ks[cur][(j * 16 + fr) * 64 + c1]);
      s[j] = __builtin_amdgcn_mfma_f32_16x16x32_bf16(k0, qa0, s[j], 0, 0, 0);
      s[j] = __builtin_amdgcn_mfma_f32_16x16x32_bf16(k1, qa1, s[j], 0, 0, 0);
    }
    unsigned mlo = (unsigned)mw, mhi = (unsigned)(mw >> 32);
#pragma unroll
    for (int j = 0; j < 4; ++j) {
      unsigned mj = ((j & 2) ? mhi : mlo) >> ((j & 1) * 16 + msh);
#pragma unroll
      for (int r = 0; r < 4; ++r) rsum += exp2f((mj & (1u << r)) ? ninf : s[j][r]);
    }
    asm volatile("s_waitcnt lgkmcnt(0)" ::: "memory");
    __builtin_amdgcn_s_barrier();
    cur ^= 1;
  }
  rsum += __shfl_xor(rsum, 16);
  rsum += __shfl_xor(rsum, 32);
  const float rs = 1.0f / rsum;

  // ================= pass 2: normalize, write attn (coalesced), PV =================
  // Ks[cur] holds tile 0 (wrap stage of pass-1 iter 31, not yet awaited).
  STAGE_V(cur, 0);
  asm volatile("s_waitcnt vmcnt(0)" ::: "memory");  // one-time drain: K0 + V0
  __builtin_amdgcn_s_barrier();
  f32x4 o[4] = {};
  const int orow = lane >> 4, ocol = (lane & 15) * 4;
  float* abase = attn_out + ((size_t)bh * 2048 + q0 + wave * 16) * 2048;

  for (int kt = 0; kt < 32; ++kt) {
    unsigned long long mw = mrow[kt];
    STAGE_K(cur ^ 1, (kt + 1) & 31);
    STAGE_V(cur ^ 1, (kt + 1) & 31);
    asm volatile("s_waitcnt vmcnt(7)" ::: "memory");  // tile-kt K+V retired
    __builtin_amdgcn_s_barrier();
    f32x4 s[4] = {};
#pragma unroll
    for (int j = 0; j < 4; ++j) {
      bf16x8 k0 = *(const bf16x8*)(&Ks[cur][(j * 16 + fr) * 64 + c0]);
      bf16x8 k1 = *(const bf16x8*)(&Ks[cur][(j * 16 + fr) * 64 + c1]);
      s[j] = __builtin_amdgcn_mfma_f32_16x16x32_bf16(k0, qa0, s[j], 0, 0, 0);
      s[j] = __builtin_amdgcn_mfma_f32_16x16x32_bf16(k1, qa1, s[j], 0, 0, 0);
    }
    unsigned mlo = (unsigned)mw, mhi = (unsigned)(mw >> 32);
    unsigned pk[4][2];
#pragma unroll
    for (int j = 0; j < 4; ++j) {
      unsigned mj = ((j & 2) ? mhi : mlo) >> ((j & 1) * 16 + msh);
      float e0 = exp2f((mj & 1u) ? ninf : s[j][0]) * rs;
      float e1 = exp2f((mj & 2u) ? ninf : s[j][1]) * rs;
      float e2 = exp2f((mj & 4u) ? ninf : s[j][2]) * rs;
      float e3 = exp2f((mj & 8u) ? ninf : s[j][3]) * rs;
      f32x4 ev;
      ev[0] = e0; ev[1] = e1; ev[2] = e2; ev[3] = e3;
      *(f32x4*)(&Os[wave][fr * 65 + j * 16 + fg * 4]) = ev;  // LDS bounce
      asm("v_cvt_pk_bf16_f32 %0, %1, %2" : "=v"(pk[j][0]) : "v"(e0), "v"(e1));
      asm("v_cvt_pk_bf16_f32 %0, %1, %2" : "=v"(pk[j][1]) : "v"(e2), "v"(e3));
    }
    // in-register P redistribution (verified round 8): swap32 then swap16 of
    // (w[2ks][p], w[2ks+1][p]) yields the two A-operand words directly.
    unsigned x0 = pk[0][0], y0 = pk[1][0], x1 = pk[0][1], y1 = pk[1][1];
    unsigned x2 = pk[2][0], y2 = pk[3][0], x3 = pk[2][1], y3 = pk[3][1];
    asm("v_permlane32_swap_b32 %0, %1" : "+v"(x0), "+v"(y0));
    asm("v_permlane16_swap_b32 %0, %1" : "+v"(x0), "+v"(y0));
    asm("v_permlane32_swap_b32 %0, %1" : "+v"(x1), "+v"(y1));
    asm("v_permlane16_swap_b32 %0, %1" : "+v"(x1), "+v"(y1));
    asm("v_permlane32_swap_b32 %0, %1" : "+v"(x2), "+v"(y2));
    asm("v_permlane16_swap_b32 %0, %1" : "+v"(x2), "+v"(y2));
    asm("v_permlane32_swap_b32 %0, %1" : "+v"(x3), "+v"(y3));
    asm("v_permlane16_swap_b32 %0, %1" : "+v"(x3), "+v"(y3));
    u32x4 t0, t1;
    t0[0] = x0; t0[1] = x1; t0[2] = y0; t0[3] = y1;
    t1[0] = x2; t1[1] = x3; t1[2] = y2; t1[3] = y3;
    bf16x8 pa0 = __builtin_bit_cast(bf16x8, t0);
    bf16x8 pa1 = __builtin_bit_cast(bf16x8, t1);
#pragma unroll
    for (int ct = 0; ct < 4; ++ct) {
      bf16x8 v0 = *(const bf16x8*)(&Vs[cur][(ct * 16 + fr) * 64 + c0]);
      bf16x8 v1 = *(const bf16x8*)(&Vs[cur][(ct * 16 + fr) * 64 + c1]);
      o[ct] = __builtin_amdgcn_mfma_f32_16x16x32_bf16(pa0, v0, o[ct], 0, 0, 0);
      o[ct] = __builtin_amdgcn_mfma_f32_16x16x32_bf16(pa1, v1, o[ct], 0, 0, 0);
    }
    // coalesced write-out: instr i writes rows {orow+4i}, lanes 0-15 = one full
    // 256B row segment (4 segments/instr vs 16x64B before)
#pragma unroll
    for (int i = 0; i < 4; ++i) {
      f32x4 ov = *(const f32x4*)(&Os[wave][(orow + 4 * i) * 65 + ocol]);
      __builtin_nontemporal_store(
          ov, (f32x4*)(abase + (size_t)(orow + 4 * i) * 2048 + kt * 64 + ocol));
    }
    asm volatile("s_waitcnt lgkmcnt(0)" ::: "memory");
    __builtin_amdgcn_s_barrier();
    cur ^= 1;
  }
#pragma unroll
  for (int ct = 0; ct < 4; ++ct)
#pragma unroll
    for (int r = 0; r < 4; ++r)
      ctx[(size_t)(b * 2048 + q0 + wave * 16 + fg * 4 + r) * 1024 + h * 64 + ct * 16 + fr] =
          f2bf(o[ct][r]);
#undef STAGE_K
#undef STAGE_V
}

// ---------------- fused residual-add + LayerNorm ----------------
__global__ __launch_bounds__(256) void ln_kernel(const float* __restrict__ resl,
                                                 const float* __restrict__ inQ,
                                                 float* __restrict__ out) {
  __shared__ float red[8];
  const int row = blockIdx.x, tid = threadIdx.x;
  const int wave = tid >> 6, lane = tid & 63;
  float4 xv = ((const float4*)(resl + (size_t)row * 1024))[tid];
  float4 qv = ((const float4*)(inQ + (size_t)row * 1024))[tid];
  float v0 = xv.x + qv.x, v1 = xv.y + qv.y, v2 = xv.z + qv.z, v3 = xv.w + qv.w;
  float s = v0 + v1 + v2 + v3;
  float s2 = v0 * v0 + v1 * v1 + v2 * v2 + v3 * v3;
#pragma unroll
  for (int off = 1; off < 64; off <<= 1) {
    s += __shfl_xor(s, off);
    s2 += __shfl_xor(s2, off);
  }
  if (lane == 0) { red[wave] = s; red[4 + wave] = s2; }
  __syncthreads();
  s = red[0] + red[1] + red[2] + red[3];
  s2 = red[4] + red[5] + red[6] + red[7];
  const float mu = s * (1.0f / 1024.0f);
  const float var = s2 * (1.0f / 1024.0f) - mu * mu;
  const float inv = rsqrtf(var + 1e-5f);
  float4 ov;
  ov.x = (v0 - mu) * inv;
  ov.y = (v1 - mu) * inv;
  ov.z = (v2 - mu) * inv;
  ov.w = (v3 - mu) * inv;
  ((float4*)(out + (size_t)row * 1024))[tid] = ov;
}

extern "C" void kernel_launch(void* const* d_in, const int* in_sizes, int n_in, void* d_out,
                              int out_size, void* d_ws, size_t ws_size, hipStream_t stream) {
  const float* inQ = (const float*)d_in[0];
  const float* inK = (const float*)d_in[1];
  const float* inV = (const float*)d_in[2];
  const int* mask = (const int*)d_in[3];
  const float* WQ = (const float*)d_in[4];
  const float* WK = (const float*)d_in[5];
  const float* WV = (const float*)d_in[6];
  const float* WF = (const float*)d_in[7];
  float* res = (float*)d_out;
  float* attn = res + (size_t)8192 * 1024;

  char* w = (char*)d_ws;
  unsigned short* inQb = (unsigned short*)w; w += (size_t)16777216;
  unsigned short* inKb = (unsigned short*)w; w += (size_t)16777216;
  unsigned short* inVb = (unsigned short*)w; w += (size_t)16777216;
  unsigned short* WQt = (unsigned short*)w; w += (size_t)2097152;
  unsigned short* WKt = (unsigned short*)w; w += (size_t)2097152;
  unsigned short* WVt = (unsigned short*)w; w += (size_t)2097152;
  unsigned short* WFt = (unsigned short*)w; w += (size_t)2097152;
  unsigned short* Qp  = (unsigned short*)w; w += (size_t)16777216;
  unsigned short* Kp  = (unsigned short*)w; w += (size_t)16777216;
  unsigned short* Vp  = (unsigned short*)w; w += (size_t)16777216;
  unsigned short* Vtb = (unsigned short*)w; w += (size_t)16777216;
  unsigned short* ctx = (unsigned short*)w; w += (size_t)16777216;
  float* resl = (float*)w; w += (size_t)33554432;
  // mask bitwords reuse inQb's space (dead after the Q projection GEMM)
  unsigned long long* mbits = (unsigned long long*)inQb;

  cvt_kernel<<<8192, 256, 0, stream>>>(inQ, inQb, 2097152);
  cvt_kernel<<<8192, 256, 0, stream>>>(inK, inKb, 2097152);
  cvt_kernel<<<8192, 256, 0, stream>>>(inV, inVb, 2097152);
  dim3 wb(32, 8);
  // fold 1/sqrt(64) * log2(e) into W_Q so attn uses exp2(S) directly
  wtrans_kernel<<<dim3(32, 32), wb, 0, stream>>>(WQ, WQt, 0.18033688f);
  wtrans_kernel<<<dim3(32, 32), wb, 0, stream>>>(WK, WKt, 1.0f);
  wtrans_kernel<<<dim3(32, 32), wb, 0, stream>>>(WV, WVt, 1.0f);
  wtrans_kernel<<<dim3(32, 32), wb, 0, stream>>>(WF, WFt, 1.0f);
  gemm_nt<false><<<512, 256, 0, stream>>>(inQb, 1024, WQt, 1024, Qp, 1024, 1024);
  gemm_nt<false><<<512, 256, 0, stream>>>(inKb, 1024, WKt, 1024, Kp, 1024, 1024);
  gemm_nt<false><<<512, 256, 0, stream>>>(inVb, 1024, WVt, 1024, Vp, 1024, 1024);
  maskbits_kernel<<<65536, 256, 0, stream>>>(mask, mbits);
  vtrans_kernel<<<dim3(32, 64), 256, 0, stream>>>(Vp, Vtb);
  attn_kernel<<<1024, 512, 0, stream>>>(Qp, Kp, Vtb, mbits, attn, ctx);
  gemm_nt<true><<<512, 256, 0, stream>>>(ctx, 1024, WFt, 1024, resl, 1024, 1024);
  ln_kernel<<<8192, 256, 0, stream>>>(resl, inQ, res);
}

// Round 14
// 470.760 us; speedup vs baseline: 1.2067x; 1.0403x over previous
//
#include <hip/hip_runtime.h>
#include <hip/hip_bf16.h>
#include <stdint.h>

#define DEVI __device__ __forceinline__

typedef __attribute__((ext_vector_type(8))) short bf16x8;
typedef __attribute__((ext_vector_type(4))) float f32x4;
typedef __attribute__((ext_vector_type(4))) unsigned u32x4;

static DEVI unsigned short f2bf(float f) {
  unsigned int u = __builtin_bit_cast(unsigned int, f);
  u = (u + 0x7FFFu + ((u >> 16) & 1u)) >> 16;
  return (unsigned short)u;
}

static DEVI void async16(const void* g, void* l) {
  __builtin_amdgcn_global_load_lds((__attribute__((address_space(1))) void*)(g),
                                   (__attribute__((address_space(3))) void*)(l),
                                   16, 0, 0);
}

// ---------------- f32 -> bf16 convert, all three inputs in one launch ----------------
__global__ __launch_bounds__(256) void cvt3_kernel(const float* __restrict__ q,
                                                   const float* __restrict__ k,
                                                   const float* __restrict__ v,
                                                   unsigned short* __restrict__ outbase) {
  int i = blockIdx.x * 256 + threadIdx.x;  // 0 .. 3*2097152-1 (uniform input per block)
  int which = i >> 21;
  int off = i & 2097151;
  const float* in = which == 0 ? q : (which == 1 ? k : v);
  float4 val = ((const float4*)in)[off];
  uint2 o;
  o.x = (unsigned)f2bf(val.x) | ((unsigned)f2bf(val.y) << 16);
  o.y = (unsigned)f2bf(val.z) | ((unsigned)f2bf(val.w) << 16);
  ((uint2*)(outbase + (size_t)which * 8388608))[off] = o;
}

// ---- mask int32 -> 1 bit per element (word w covers cols [w*64, w*64+64)) ----
__global__ __launch_bounds__(256) void maskbits_kernel(const int* __restrict__ mask,
                                                       unsigned long long* __restrict__ mb) {
  size_t tg = (size_t)blockIdx.x * 256 + threadIdx.x;
  int v = mask[tg];
  unsigned long long bal = __ballot(v != 0);
  if ((threadIdx.x & 63) == 0) mb[tg >> 6] = bal;
}

// ---- all 4 weights: W [1024 in][1024 out] f32 -> Wt [out][in] bf16 (+scale), one launch ----
__global__ __launch_bounds__(256) void wtrans4_kernel(const float* __restrict__ W0,
                                                      const float* __restrict__ W1,
                                                      const float* __restrict__ W2,
                                                      const float* __restrict__ W3,
                                                      unsigned short* __restrict__ Wtbase) {
  __shared__ float t[32][33];
  const int z = blockIdx.z;
  const float* W = z == 0 ? W0 : (z == 1 ? W1 : (z == 2 ? W2 : W3));
  unsigned short* Wt = Wtbase + (size_t)z * 1048576;
  const float scale = (z == 0) ? 0.18033688f : 1.0f;  // fold 0.125*log2e into W_Q
  const int bx = blockIdx.x * 32;  // out (n)
  const int by = blockIdx.y * 32;  // in (k)
  const int tx = threadIdx.x, ty = threadIdx.y;  // 32 x 8
#pragma unroll
  for (int i = 0; i < 32; i += 8) t[ty + i][tx] = W[(size_t)(by + ty + i) * 1024 + bx + tx];
  __syncthreads();
#pragma unroll
  for (int i = 0; i < 32; i += 8)
    Wt[(size_t)(bx + ty + i) * 1024 + by + tx] = f2bf(t[tx][ty + i] * scale);
}

// ---- fused Q/K/V projection GEMM: 3 x (C[8192,1024] = A[8192,1024] * B[1024,1024]^T) ----
// grid 1536 = 3 x 512; which = g>>9 selects (A,B,C) by contiguous-ws stride.
// Within each 512: XCD remap (g&7 preserved since 512 % 8 == 0).
__global__ __launch_bounds__(256) void gemm_qkv(const unsigned short* __restrict__ Abase,
                                                const unsigned short* __restrict__ Bbase,
                                                unsigned short* __restrict__ Cbase) {
  __shared__ unsigned short As[128 * 64];
  __shared__ unsigned short Bs[128 * 64];
  const int tid = threadIdx.x;
  const int wave = tid >> 6, lane = tid & 63;
  const int g = blockIdx.x;
  const int which = g >> 9, sub = g & 511;
  const unsigned short* A = Abase + (size_t)which * 8388608;
  const unsigned short* B = Bbase + (size_t)which * 1048576;
  unsigned short* C = Cbase + (size_t)which * 8388608;
  const int xcd = sub & 7, i4 = sub >> 3;
  const int m0 = (xcd * 8 + (i4 >> 3)) * 128;
  const int n0 = (i4 & 7) * 128;
  const int wr = (wave >> 1) * 64, wc = (wave & 1) * 64;
  const int fr = lane & 15, fg = lane >> 4;
  f32x4 acc[4][4] = {};
  for (int kt = 0; kt < 1024; kt += 64) {
    __syncthreads();
#pragma unroll
    for (int it = 0; it < 4; ++it) {
      int id = it * 256 + tid;
      int row = id >> 3, ch = id & 7;
      async16(A + (size_t)(m0 + row) * 1024 + kt + ch * 8,
              (char*)As + (it * 256 + wave * 64) * 16);
      async16(B + (size_t)(n0 + row) * 1024 + kt + ch * 8,
              (char*)Bs + (it * 256 + wave * 64) * 16);
    }
    __syncthreads();
#pragma unroll
    for (int ks = 0; ks < 2; ++ks) {
      bf16x8 af[4], bfr[4];
#pragma unroll
      for (int i = 0; i < 4; ++i)
        af[i] = *(const bf16x8*)(As + (wr + i * 16 + fr) * 64 + ks * 32 + fg * 8);
#pragma unroll
      for (int j = 0; j < 4; ++j)
        bfr[j] = *(const bf16x8*)(Bs + (wc + j * 16 + fr) * 64 + ks * 32 + fg * 8);
#pragma unroll
      for (int i = 0; i < 4; ++i)
#pragma unroll
        for (int j = 0; j < 4; ++j)
          acc[i][j] = __builtin_amdgcn_mfma_f32_16x16x32_bf16(af[i], bfr[j], acc[i][j], 0, 0, 0);
    }
  }
#pragma unroll
  for (int i = 0; i < 4; ++i)
#pragma unroll
    for (int j = 0; j < 4; ++j)
#pragma unroll
      for (int r = 0; r < 4; ++r)
        C[(size_t)(m0 + wr + i * 16 + fg * 4 + r) * 1024 + n0 + wc + j * 16 + fr] =
            f2bf(acc[i][j][r]);
}

// ---- fc GEMM with fused residual add: C[M,N] = ctx * Wfc^T + inQ (f32 out) ----
__global__ __launch_bounds__(256) void gemm_fc(const unsigned short* __restrict__ A,
                                               const unsigned short* __restrict__ B,
                                               float* __restrict__ C,
                                               const float* __restrict__ R) {
  __shared__ unsigned short As[128 * 64];
  __shared__ unsigned short Bs[128 * 64];
  const int tid = threadIdx.x;
  const int wave = tid >> 6, lane = tid & 63;
  const int g = blockIdx.x;
  const int xcd = g & 7, i4 = g >> 3;
  const int m0 = (xcd * 8 + (i4 >> 3)) * 128;
  const int n0 = (i4 & 7) * 128;
  const int wr = (wave >> 1) * 64, wc = (wave & 1) * 64;
  const int fr = lane & 15, fg = lane >> 4;
  f32x4 acc[4][4] = {};
  for (int kt = 0; kt < 1024; kt += 64) {
    __syncthreads();
#pragma unroll
    for (int it = 0; it < 4; ++it) {
      int id = it * 256 + tid;
      int row = id >> 3, ch = id & 7;
      async16(A + (size_t)(m0 + row) * 1024 + kt + ch * 8,
              (char*)As + (it * 256 + wave * 64) * 16);
      async16(B + (size_t)(n0 + row) * 1024 + kt + ch * 8,
              (char*)Bs + (it * 256 + wave * 64) * 16);
    }
    __syncthreads();
#pragma unroll
    for (int ks = 0; ks < 2; ++ks) {
      bf16x8 af[4], bfr[4];
#pragma unroll
      for (int i = 0; i < 4; ++i)
        af[i] = *(const bf16x8*)(As + (wr + i * 16 + fr) * 64 + ks * 32 + fg * 8);
#pragma unroll
      for (int j = 0; j < 4; ++j)
        bfr[j] = *(const bf16x8*)(Bs + (wc + j * 16 + fr) * 64 + ks * 32 + fg * 8);
#pragma unroll
      for (int i = 0; i < 4; ++i)
#pragma unroll
        for (int j = 0; j < 4; ++j)
          acc[i][j] = __builtin_amdgcn_mfma_f32_16x16x32_bf16(af[i], bfr[j], acc[i][j], 0, 0, 0);
    }
  }
#pragma unroll
  for (int i = 0; i < 4; ++i)
#pragma unroll
    for (int j = 0; j < 4; ++j)
#pragma unroll
      for (int r = 0; r < 4; ++r) {
        size_t idx = (size_t)(m0 + wr + i * 16 + fg * 4 + r) * 1024 + n0 + wc + j * 16 + fr;
        C[idx] = acc[i][j][r] + R[idx];
      }
}

// ---- Vp [b*2048+l][h*64+d] bf16 -> Vt [bh][d][l] bf16 (per-head transpose) ----
__global__ __launch_bounds__(256) void vtrans_kernel(const unsigned short* __restrict__ Vp,
                                                     unsigned short* __restrict__ Vt) {
  __shared__ unsigned short t[64][72];
  const int bh = blockIdx.y;
  const int b = bh >> 4, h = bh & 15;
  const int l0 = blockIdx.x * 64;
  const int tid = threadIdx.x;
#pragma unroll
  for (int it = 0; it < 2; ++it) {
    int id = it * 256 + tid;
    int l = id >> 3, ch = id & 7;
    uint4 v = *(const uint4*)(Vp + (size_t)(b * 2048 + l0 + l) * 1024 + h * 64 + ch * 8);
    *(uint4*)(&t[l][ch * 8]) = v;
  }
  __syncthreads();
#pragma unroll
  for (int it = 0; it < 2; ++it) {
    int id = it * 256 + tid;
    int d = id >> 3, lc = id & 7;
    unsigned short o[8];
#pragma unroll
    for (int k = 0; k < 8; ++k) o[k] = t[lc * 8 + k][d];
    uint4 ov;
    ov.x = o[0] | ((unsigned)o[1] << 16);
    ov.y = o[2] | ((unsigned)o[3] << 16);
    ov.z = o[4] | ((unsigned)o[5] << 16);
    ov.w = o[6] | ((unsigned)o[7] << 16);
    *(uint4*)(Vt + ((size_t)bh * 64 + d) * 2048 + l0 + lc * 8) = ov;
  }
}

// ------ fused attention (round-11 kernel VERBATIM — best known) ------
// grid 1024 = 8 XCD x 8 bh x 16 q-tiles, 512 threads (8 waves x 16 q-rows).
// LDS-bounced coalesced attn stores ([16][65] f32 bounce -> 4x256B contiguous
// segments per instr). FIFO waits: pass1 vmcnt(2), pass2 vmcnt(7).
__global__ __launch_bounds__(512, 4) void attn_kernel(
    const unsigned short* __restrict__ Qp, const unsigned short* __restrict__ Kp,
    const unsigned short* __restrict__ Vt, const unsigned long long* __restrict__ mb,
    float* __restrict__ attn_out, unsigned short* __restrict__ ctx) {
  __shared__ unsigned short Ks[2][4096];
  __shared__ unsigned short Vs[2][4096];
  __shared__ float Os[8][16 * 65];
  const int tid = threadIdx.x, wave = tid >> 6, lane = tid & 63;
  const int g = blockIdx.x;
  const int idx = g >> 3;
  const int bh = (g & 7) * 8 + (idx >> 4);  // same-XCD blocks share 8 heads
  const int b = bh >> 4, h = bh & 15;
  const int q0 = (idx & 15) * 128;
  const int fr = lane & 15, fg = lane >> 4;
  const int q = q0 + wave * 16 + fr;  // this lane's q row

  // ---- staging coords: thread covers row r0 (of 64), chunk pre-swizzled ----
  const int r0 = tid >> 3;
  const int chs = ((tid & 7) ^ (r0 & 7)) << 3;  // swizzled u16 chunk offset
  const unsigned short* kg = Kp + (size_t)(b * 2048 + r0) * 1024 + h * 64 + chs;
  const unsigned short* vg = Vt + (size_t)bh * 131072 + (size_t)r0 * 2048 + chs;

#define STAGE_K(buf, t) async16(kg + (size_t)(t) * 65536, (char*)Ks[buf] + wave * 1024)
#define STAGE_V(buf, t) async16(vg + (t) * 64, (char*)Vs[buf] + wave * 1024)

  // ---- fragment read offsets (swizzle involution on chunk) ----
  const int c0 = (fg ^ (fr & 7)) << 3;        // ks=0 chunk
  const int c1 = ((4 + fg) ^ (fr & 7)) << 3;  // ks=1 chunk

  // Q fragment (B-operand), scale pre-folded into W_Q
  const unsigned short* qbase = Qp + (size_t)(b * 2048 + q) * 1024 + h * 64 + fg * 8;
  bf16x8 qa0 = *(const bf16x8*)(qbase);
  bf16x8 qa1 = *(const bf16x8*)(qbase + 32);

  const unsigned long long* mrow = mb + (size_t)(b * 2048 + q) * 32;
  const int msh = fg * 4;
  const float ninf = __uint_as_float(0xFF800000u);

  // ================= pass 1: row sums of exp2(S) =================
  STAGE_K(0, 0);
  int cur = 0;
  float rsum = 0.f;
  for (int kt = 0; kt < 32; ++kt) {
    unsigned long long mw = mrow[kt];
    STAGE_K(cur ^ 1, (kt + 1) & 31);
    asm volatile("s_waitcnt vmcnt(2)" ::: "memory");  // tile-kt K retired
    __builtin_amdgcn_s_barrier();
    f32x4 s[4] = {};
#pragma unroll
    for (int j = 0; j < 4; ++j) {
      bf16x8 k0 = *(const bf16x8*)(&Ks[cur][(j * 16 + fr) * 64 + c0]);
      bf16x8 k1 = *(const bf16x8*)(&Ks[cur][(j * 16 + fr) * 64 + c1]);
      s[j] = __builtin_amdgcn_mfma_f32_16x16x32_bf16(k0, qa0, s[j], 0, 0, 0);
      s[j] = __builtin_amdgcn_mfma_f32_16x16x32_bf16(k1, qa1, s[j], 0, 0, 0);
    }
    unsigned mlo = (unsigned)mw, mhi = (unsigned)(mw >> 32);
#pragma unroll
    for (int j = 0; j < 4; ++j) {
      unsigned mj = ((j & 2) ? mhi : mlo) >> ((j & 1) * 16 + msh);
#pragma unroll
      for (int r = 0; r < 4; ++r) rsum += exp2f((mj & (1u << r)) ? ninf : s[j][r]);
    }
    asm volatile("s_waitcnt lgkmcnt(0)" ::: "memory");
    __builtin_amdgcn_s_barrier();
    cur ^= 1;
  }
  rsum += __shfl_xor(rsum, 16);
  rsum += __shfl_xor(rsum, 32);
  const float rs = 1.0f / rsum;

  // ================= pass 2: normalize, write attn (coalesced), PV =================
  // Ks[cur] holds tile 0 (wrap stage of pass-1 iter 31, not yet awaited).
  STAGE_V(cur, 0);
  asm volatile("s_waitcnt vmcnt(0)" ::: "memory");  // one-time drain: K0 + V0
  __builtin_amdgcn_s_barrier();
  f32x4 o[4] = {};
  const int orow = lane >> 4, ocol = (lane & 15) * 4;
  float* abase = attn_out + ((size_t)bh * 2048 + q0 + wave * 16) * 2048;

  for (int kt = 0; kt < 32; ++kt) {
    unsigned long long mw = mrow[kt];
    STAGE_K(cur ^ 1, (kt + 1) & 31);
    STAGE_V(cur ^ 1, (kt + 1) & 31);
    asm volatile("s_waitcnt vmcnt(7)" ::: "memory");  // tile-kt K+V retired
    __builtin_amdgcn_s_barrier();
    f32x4 s[4] = {};
#pragma unroll
    for (int j = 0; j < 4; ++j) {
      bf16x8 k0 = *(const bf16x8*)(&Ks[cur][(j * 16 + fr) * 64 + c0]);
      bf16x8 k1 = *(const bf16x8*)(&Ks[cur][(j * 16 + fr) * 64 + c1]);
      s[j] = __builtin_amdgcn_mfma_f32_16x16x32_bf16(k0, qa0, s[j], 0, 0, 0);
      s[j] = __builtin_amdgcn_mfma_f32_16x16x32_bf16(k1, qa1, s[j], 0, 0, 0);
    }
    unsigned mlo = (unsigned)mw, mhi = (unsigned)(mw >> 32);
    unsigned pk[4][2];
#pragma unroll
    for (int j = 0; j < 4; ++j) {
      unsigned mj = ((j & 2) ? mhi : mlo) >> ((j & 1) * 16 + msh);
      float e0 = exp2f((mj & 1u) ? ninf : s[j][0]) * rs;
      float e1 = exp2f((mj & 2u) ? ninf : s[j][1]) * rs;
      float e2 = exp2f((mj & 4u) ? ninf : s[j][2]) * rs;
      float e3 = exp2f((mj & 8u) ? ninf : s[j][3]) * rs;
      f32x4 ev;
      ev[0] = e0; ev[1] = e1; ev[2] = e2; ev[3] = e3;
      *(f32x4*)(&Os[wave][fr * 65 + j * 16 + fg * 4]) = ev;  // LDS bounce
      asm("v_cvt_pk_bf16_f32 %0, %1, %2" : "=v"(pk[j][0]) : "v"(e0), "v"(e1));
      asm("v_cvt_pk_bf16_f32 %0, %1, %2" : "=v"(pk[j][1]) : "v"(e2), "v"(e3));
    }
    // in-register P redistribution (verified round 8): swap32 then swap16 of
    // (w[2ks][p], w[2ks+1][p]) yields the two A-operand words directly.
    unsigned x0 = pk[0][0], y0 = pk[1][0], x1 = pk[0][1], y1 = pk[1][1];
    unsigned x2 = pk[2][0], y2 = pk[3][0], x3 = pk[2][1], y3 = pk[3][1];
    asm("v_permlane32_swap_b32 %0, %1" : "+v"(x0), "+v"(y0));
    asm("v_permlane16_swap_b32 %0, %1" : "+v"(x0), "+v"(y0));
    asm("v_permlane32_swap_b32 %0, %1" : "+v"(x1), "+v"(y1));
    asm("v_permlane16_swap_b32 %0, %1" : "+v"(x1), "+v"(y1));
    asm("v_permlane32_swap_b32 %0, %1" : "+v"(x2), "+v"(y2));
    asm("v_permlane16_swap_b32 %0, %1" : "+v"(x2), "+v"(y2));
    asm("v_permlane32_swap_b32 %0, %1" : "+v"(x3), "+v"(y3));
    asm("v_permlane16_swap_b32 %0, %1" : "+v"(x3), "+v"(y3));
    u32x4 t0, t1;
    t0[0] = x0; t0[1] = x1; t0[2] = y0; t0[3] = y1;
    t1[0] = x2; t1[1] = x3; t1[2] = y2; t1[3] = y3;
    bf16x8 pa0 = __builtin_bit_cast(bf16x8, t0);
    bf16x8 pa1 = __builtin_bit_cast(bf16x8, t1);
#pragma unroll
    for (int ct = 0; ct < 4; ++ct) {
      bf16x8 v0 = *(const bf16x8*)(&Vs[cur][(ct * 16 + fr) * 64 + c0]);
      bf16x8 v1 = *(const bf16x8*)(&Vs[cur][(ct * 16 + fr) * 64 + c1]);
      o[ct] = __builtin_amdgcn_mfma_f32_16x16x32_bf16(pa0, v0, o[ct], 0, 0, 0);
      o[ct] = __builtin_amdgcn_mfma_f32_16x16x32_bf16(pa1, v1, o[ct], 0, 0, 0);
    }
    // coalesced write-out: instr i writes rows {orow+4i}, lanes 0-15 = one full
    // 256B row segment (4 segments/instr vs 16x64B before)
#pragma unroll
    for (int i = 0; i < 4; ++i) {
      f32x4 ov = *(const f32x4*)(&Os[wave][(orow + 4 * i) * 65 + ocol]);
      __builtin_nontemporal_store(
          ov, (f32x4*)(abase + (size_t)(orow + 4 * i) * 2048 + kt * 64 + ocol));
    }
    asm volatile("s_waitcnt lgkmcnt(0)" ::: "memory");
    __builtin_amdgcn_s_barrier();
    cur ^= 1;
  }
#pragma unroll
  for (int ct = 0; ct < 4; ++ct)
#pragma unroll
    for (int r = 0; r < 4; ++r)
      ctx[(size_t)(b * 2048 + q0 + wave * 16 + fg * 4 + r) * 1024 + h * 64 + ct * 16 + fr] =
          f2bf(o[ct][r]);
#undef STAGE_K
#undef STAGE_V
}

// ---------------- LayerNorm (residual already added by gemm_fc) ----------------
__global__ __launch_bounds__(256) void ln_kernel(const float* __restrict__ resl,
                                                 float* __restrict__ out) {
  __shared__ float red[8];
  const int row = blockIdx.x, tid = threadIdx.x;
  const int wave = tid >> 6, lane = tid & 63;
  float4 xv = ((const float4*)(resl + (size_t)row * 1024))[tid];
  float v0 = xv.x, v1 = xv.y, v2 = xv.z, v3 = xv.w;
  float s = v0 + v1 + v2 + v3;
  float s2 = v0 * v0 + v1 * v1 + v2 * v2 + v3 * v3;
#pragma unroll
  for (int off = 1; off < 64; off <<= 1) {
    s += __shfl_xor(s, off);
    s2 += __shfl_xor(s2, off);
  }
  if (lane == 0) { red[wave] = s; red[4 + wave] = s2; }
  __syncthreads();
  s = red[0] + red[1] + red[2] + red[3];
  s2 = red[4] + red[5] + red[6] + red[7];
  const float mu = s * (1.0f / 1024.0f);
  const float var = s2 * (1.0f / 1024.0f) - mu * mu;
  const float inv = rsqrtf(var + 1e-5f);
  float4 ov;
  ov.x = (v0 - mu) * inv;
  ov.y = (v1 - mu) * inv;
  ov.z = (v2 - mu) * inv;
  ov.w = (v3 - mu) * inv;
  ((float4*)(out + (size_t)row * 1024))[tid] = ov;
}

extern "C" void kernel_launch(void* const* d_in, const int* in_sizes, int n_in, void* d_out,
                              int out_size, void* d_ws, size_t ws_size, hipStream_t stream) {
  const float* inQ = (const float*)d_in[0];
  const float* inK = (const float*)d_in[1];
  const float* inV = (const float*)d_in[2];
  const int* mask = (const int*)d_in[3];
  const float* WQ = (const float*)d_in[4];
  const float* WK = (const float*)d_in[5];
  const float* WV = (const float*)d_in[6];
  const float* WF = (const float*)d_in[7];
  float* res = (float*)d_out;
  float* attn = res + (size_t)8192 * 1024;

  char* w = (char*)d_ws;
  unsigned short* inQb = (unsigned short*)w; w += (size_t)16777216;   // 3x contiguous
  unsigned short* inKb = (unsigned short*)w; w += (size_t)16777216;
  unsigned short* inVb = (unsigned short*)w; w += (size_t)16777216;
  unsigned short* WQt = (unsigned short*)w; w += (size_t)2097152;     // 4x contiguous
  unsigned short* WKt = (unsigned short*)w; w += (size_t)2097152;
  unsigned short* WVt = (unsigned short*)w; w += (size_t)2097152;
  unsigned short* WFt = (unsigned short*)w; w += (size_t)2097152;
  unsigned short* Qp  = (unsigned short*)w; w += (size_t)16777216;    // 3x contiguous
  unsigned short* Kp  = (unsigned short*)w; w += (size_t)16777216;
  unsigned short* Vp  = (unsigned short*)w; w += (size_t)16777216;
  unsigned short* Vtb = (unsigned short*)w; w += (size_t)16777216;
  unsigned short* ctx = (unsigned short*)w; w += (size_t)16777216;
  float* resl = (float*)w; w += (size_t)33554432;
  // mask bitwords reuse inQb's space (dead after the QKV projection GEMM)
  unsigned long long* mbits = (unsigned long long*)inQb;
  (void)inKb; (void)inVb; (void)WKt; (void)WVt; (void)Kp;

  cvt3_kernel<<<24576, 256, 0, stream>>>(inQ, inK, inV, inQb);
  wtrans4_kernel<<<dim3(32, 32, 4), dim3(32, 8), 0, stream>>>(WQ, WK, WV, WF, WQt);
  gemm_qkv<<<1536, 256, 0, stream>>>(inQb, WQt, Qp);
  maskbits_kernel<<<65536, 256, 0, stream>>>(mask, mbits);
  vtrans_kernel<<<dim3(32, 64), 256, 0, stream>>>(Vp, Vtb);
  attn_kernel<<<1024, 512, 0, stream>>>(Qp, Kp, Vtb, mbits, attn, ctx);
  gemm_fc<<<512, 256, 0, stream>>>(ctx, WFt, resl, inQ);
  ln_kernel<<<8192, 256, 0, stream>>>(resl, res);
}

// Round 15
// 464.976 us; speedup vs baseline: 1.2217x; 1.0124x over previous
//
#include <hip/hip_runtime.h>
#include <hip/hip_bf16.h>
#include <stdint.h>

#define DEVI __device__ __forceinline__

typedef __attribute__((ext_vector_type(8))) short bf16x8;
typedef __attribute__((ext_vector_type(4))) float f32x4;
typedef __attribute__((ext_vector_type(4))) unsigned u32x4;

static DEVI unsigned short f2bf(float f) {
  unsigned int u = __builtin_bit_cast(unsigned int, f);
  u = (u + 0x7FFFu + ((u >> 16) & 1u)) >> 16;
  return (unsigned short)u;
}

static DEVI void async16(const void* g, void* l) {
  __builtin_amdgcn_global_load_lds((__attribute__((address_space(1))) void*)(g),
                                   (__attribute__((address_space(3))) void*)(l),
                                   16, 0, 0);
}

// ---------------- f32 -> bf16 convert, all three inputs in one launch ----------------
__global__ __launch_bounds__(256) void cvt3_kernel(const float* __restrict__ q,
                                                   const float* __restrict__ k,
                                                   const float* __restrict__ v,
                                                   unsigned short* __restrict__ outbase) {
  int i = blockIdx.x * 256 + threadIdx.x;  // 0 .. 3*2097152-1 (uniform input per block)
  int which = i >> 21;
  int off = i & 2097151;
  const float* in = which == 0 ? q : (which == 1 ? k : v);
  float4 val = ((const float4*)in)[off];
  uint2 o;
  o.x = (unsigned)f2bf(val.x) | ((unsigned)f2bf(val.y) << 16);
  o.y = (unsigned)f2bf(val.z) | ((unsigned)f2bf(val.w) << 16);
  ((uint2*)(outbase + (size_t)which * 8388608))[off] = o;
}

// ---- mask int32 -> 1 bit per element (word w covers cols [w*64, w*64+64)) ----
__global__ __launch_bounds__(256) void maskbits_kernel(const int* __restrict__ mask,
                                                       unsigned long long* __restrict__ mb) {
  size_t tg = (size_t)blockIdx.x * 256 + threadIdx.x;
  int v = mask[tg];
  unsigned long long bal = __ballot(v != 0);
  if ((threadIdx.x & 63) == 0) mb[tg >> 6] = bal;
}

// ---- all 4 weights: W [1024 in][1024 out] f32 -> Wt [out][in] bf16 (+scale), one launch ----
__global__ __launch_bounds__(256) void wtrans4_kernel(const float* __restrict__ W0,
                                                      const float* __restrict__ W1,
                                                      const float* __restrict__ W2,
                                                      const float* __restrict__ W3,
                                                      unsigned short* __restrict__ Wtbase) {
  __shared__ float t[32][33];
  const int z = blockIdx.z;
  const float* W = z == 0 ? W0 : (z == 1 ? W1 : (z == 2 ? W2 : W3));
  unsigned short* Wt = Wtbase + (size_t)z * 1048576;
  const float scale = (z == 0) ? 0.18033688f : 1.0f;  // fold 0.125*log2e into W_Q
  const int bx = blockIdx.x * 32;  // out (n)
  const int by = blockIdx.y * 32;  // in (k)
  const int tx = threadIdx.x, ty = threadIdx.y;  // 32 x 8
#pragma unroll
  for (int i = 0; i < 32; i += 8) t[ty + i][tx] = W[(size_t)(by + ty + i) * 1024 + bx + tx];
  __syncthreads();
#pragma unroll
  for (int i = 0; i < 32; i += 8)
    Wt[(size_t)(bx + ty + i) * 1024 + by + tx] = f2bf(t[tx][ty + i] * scale);
}

// ---- fused Q/K/V projection GEMM: 3 x (C[8192,1024] = A[8192,1024] * B[1024,1024]^T) ----
// grid 1536 = 3 x 512; which = g>>9 selects (A,B,C) by contiguous-ws stride.
// Within each 512: XCD remap (g&7 preserved since 512 % 8 == 0).
// which==2 (V): epilogue transposes the tile through LDS (As/Bs dead after K-loop)
// and writes Vt [bh][d][l] DIRECTLY with 256B-contiguous segments; Vp never written,
// vtrans kernel eliminated (-100 MB traffic).
__global__ __launch_bounds__(256) void gemm_qkv(const unsigned short* __restrict__ Abase,
                                                const unsigned short* __restrict__ Bbase,
                                                unsigned short* __restrict__ Cbase,
                                                unsigned short* __restrict__ Vt) {
  __shared__ unsigned short sm[17408];  // As[8192] | Bs[8192]; reused as T[128][136]
  unsigned short* As = sm;
  unsigned short* Bs = sm + 8192;
  const int tid = threadIdx.x;
  const int wave = tid >> 6, lane = tid & 63;
  const int g = blockIdx.x;
  const int which = g >> 9, sub = g & 511;
  const unsigned short* A = Abase + (size_t)which * 8388608;
  const unsigned short* B = Bbase + (size_t)which * 1048576;
  unsigned short* C = Cbase + (size_t)which * 8388608;
  const int xcd = sub & 7, i4 = sub >> 3;
  const int m0 = (xcd * 8 + (i4 >> 3)) * 128;
  const int n0 = (i4 & 7) * 128;
  const int wr = (wave >> 1) * 64, wc = (wave & 1) * 64;
  const int fr = lane & 15, fg = lane >> 4;
  f32x4 acc[4][4] = {};
  for (int kt = 0; kt < 1024; kt += 64) {
    __syncthreads();
#pragma unroll
    for (int it = 0; it < 4; ++it) {
      int id = it * 256 + tid;
      int row = id >> 3, ch = id & 7;
      async16(A + (size_t)(m0 + row) * 1024 + kt + ch * 8,
              (char*)As + (it * 256 + wave * 64) * 16);
      async16(B + (size_t)(n0 + row) * 1024 + kt + ch * 8,
              (char*)Bs + (it * 256 + wave * 64) * 16);
    }
    __syncthreads();
#pragma unroll
    for (int ks = 0; ks < 2; ++ks) {
      bf16x8 af[4], bfr[4];
#pragma unroll
      for (int i = 0; i < 4; ++i)
        af[i] = *(const bf16x8*)(As + (wr + i * 16 + fr) * 64 + ks * 32 + fg * 8);
#pragma unroll
      for (int j = 0; j < 4; ++j)
        bfr[j] = *(const bf16x8*)(Bs + (wc + j * 16 + fr) * 64 + ks * 32 + fg * 8);
#pragma unroll
      for (int i = 0; i < 4; ++i)
#pragma unroll
        for (int j = 0; j < 4; ++j)
          acc[i][j] = __builtin_amdgcn_mfma_f32_16x16x32_bf16(af[i], bfr[j], acc[i][j], 0, 0, 0);
    }
  }
  if (which != 2) {
#pragma unroll
    for (int i = 0; i < 4; ++i)
#pragma unroll
      for (int j = 0; j < 4; ++j)
#pragma unroll
        for (int r = 0; r < 4; ++r)
          C[(size_t)(m0 + wr + i * 16 + fg * 4 + r) * 1024 + n0 + wc + j * 16 + fr] =
              f2bf(acc[i][j][r]);
  } else {
    // transpose tile through LDS: T[col_local][row_local], stride 136 u16
    // (writes 2 lanes/bank = free; 272B row stride keeps uint4 reads 16B-aligned)
    __syncthreads();  // all MFMA reads of As/Bs done
#pragma unroll
    for (int i = 0; i < 4; ++i)
#pragma unroll
      for (int j = 0; j < 4; ++j)
#pragma unroll
        for (int r = 0; r < 4; ++r)
          sm[(wc + j * 16 + fr) * 136 + wr + i * 16 + fg * 4 + r] = f2bf(acc[i][j][r]);
    __syncthreads();
    const int b = m0 >> 11, l0 = m0 & 2047;
#pragma unroll
    for (int it = 0; it < 8; ++it) {
      int c = it * 16 + (tid >> 4);
      int hl = n0 + c;
      size_t vrow = (size_t)(b * 16 + (hl >> 6)) * 64 + (hl & 63);  // bh*64 + d
      *(uint4*)(Vt + vrow * 2048 + l0 + (tid & 15) * 8) =
          *(const uint4*)(&sm[c * 136 + (tid & 15) * 8]);
    }
  }
}

// ---- fc GEMM with fused residual add: C[M,N] = ctx * Wfc^T + inQ (f32 out) ----
__global__ __launch_bounds__(256) void gemm_fc(const unsigned short* __restrict__ A,
                                               const unsigned short* __restrict__ B,
                                               float* __restrict__ C,
                                               const float* __restrict__ R) {
  __shared__ unsigned short As[128 * 64];
  __shared__ unsigned short Bs[128 * 64];
  const int tid = threadIdx.x;
  const int wave = tid >> 6, lane = tid & 63;
  const int g = blockIdx.x;
  const int xcd = g & 7, i4 = g >> 3;
  const int m0 = (xcd * 8 + (i4 >> 3)) * 128;
  const int n0 = (i4 & 7) * 128;
  const int wr = (wave >> 1) * 64, wc = (wave & 1) * 64;
  const int fr = lane & 15, fg = lane >> 4;
  f32x4 acc[4][4] = {};
  for (int kt = 0; kt < 1024; kt += 64) {
    __syncthreads();
#pragma unroll
    for (int it = 0; it < 4; ++it) {
      int id = it * 256 + tid;
      int row = id >> 3, ch = id & 7;
      async16(A + (size_t)(m0 + row) * 1024 + kt + ch * 8,
              (char*)As + (it * 256 + wave * 64) * 16);
      async16(B + (size_t)(n0 + row) * 1024 + kt + ch * 8,
              (char*)Bs + (it * 256 + wave * 64) * 16);
    }
    __syncthreads();
#pragma unroll
    for (int ks = 0; ks < 2; ++ks) {
      bf16x8 af[4], bfr[4];
#pragma unroll
      for (int i = 0; i < 4; ++i)
        af[i] = *(const bf16x8*)(As + (wr + i * 16 + fr) * 64 + ks * 32 + fg * 8);
#pragma unroll
      for (int j = 0; j < 4; ++j)
        bfr[j] = *(const bf16x8*)(Bs + (wc + j * 16 + fr) * 64 + ks * 32 + fg * 8);
#pragma unroll
      for (int i = 0; i < 4; ++i)
#pragma unroll
        for (int j = 0; j < 4; ++j)
          acc[i][j] = __builtin_amdgcn_mfma_f32_16x16x32_bf16(af[i], bfr[j], acc[i][j], 0, 0, 0);
    }
  }
#pragma unroll
  for (int i = 0; i < 4; ++i)
#pragma unroll
    for (int j = 0; j < 4; ++j)
#pragma unroll
      for (int r = 0; r < 4; ++r) {
        size_t idx = (size_t)(m0 + wr + i * 16 + fg * 4 + r) * 1024 + n0 + wc + j * 16 + fr;
        C[idx] = acc[i][j][r] + R[idx];
      }
}

// ------ fused attention (round-11 kernel VERBATIM — best known) ------
// grid 1024 = 8 XCD x 8 bh x 16 q-tiles, 512 threads (8 waves x 16 q-rows).
// LDS-bounced coalesced attn stores ([16][65] f32 bounce -> 4x256B contiguous
// segments per instr). FIFO waits: pass1 vmcnt(2), pass2 vmcnt(7).
__global__ __launch_bounds__(512, 4) void attn_kernel(
    const unsigned short* __restrict__ Qp, const unsigned short* __restrict__ Kp,
    const unsigned short* __restrict__ Vt, const unsigned long long* __restrict__ mb,
    float* __restrict__ attn_out, unsigned short* __restrict__ ctx) {
  __shared__ unsigned short Ks[2][4096];
  __shared__ unsigned short Vs[2][4096];
  __shared__ float Os[8][16 * 65];
  const int tid = threadIdx.x, wave = tid >> 6, lane = tid & 63;
  const int g = blockIdx.x;
  const int idx = g >> 3;
  const int bh = (g & 7) * 8 + (idx >> 4);  // same-XCD blocks share 8 heads
  const int b = bh >> 4, h = bh & 15;
  const int q0 = (idx & 15) * 128;
  const int fr = lane & 15, fg = lane >> 4;
  const int q = q0 + wave * 16 + fr;  // this lane's q row

  // ---- staging coords: thread covers row r0 (of 64), chunk pre-swizzled ----
  const int r0 = tid >> 3;
  const int chs = ((tid & 7) ^ (r0 & 7)) << 3;  // swizzled u16 chunk offset
  const unsigned short* kg = Kp + (size_t)(b * 2048 + r0) * 1024 + h * 64 + chs;
  const unsigned short* vg = Vt + (size_t)bh * 131072 + (size_t)r0 * 2048 + chs;

#define STAGE_K(buf, t) async16(kg + (size_t)(t) * 65536, (char*)Ks[buf] + wave * 1024)
#define STAGE_V(buf, t) async16(vg + (t) * 64, (char*)Vs[buf] + wave * 1024)

  // ---- fragment read offsets (swizzle involution on chunk) ----
  const int c0 = (fg ^ (fr & 7)) << 3;        // ks=0 chunk
  const int c1 = ((4 + fg) ^ (fr & 7)) << 3;  // ks=1 chunk

  // Q fragment (B-operand), scale pre-folded into W_Q
  const unsigned short* qbase = Qp + (size_t)(b * 2048 + q) * 1024 + h * 64 + fg * 8;
  bf16x8 qa0 = *(const bf16x8*)(qbase);
  bf16x8 qa1 = *(const bf16x8*)(qbase + 32);

  const unsigned long long* mrow = mb + (size_t)(b * 2048 + q) * 32;
  const int msh = fg * 4;
  const float ninf = __uint_as_float(0xFF800000u);

  // ================= pass 1: row sums of exp2(S) =================
  STAGE_K(0, 0);
  int cur = 0;
  float rsum = 0.f;
  for (int kt = 0; kt < 32; ++kt) {
    unsigned long long mw = mrow[kt];
    STAGE_K(cur ^ 1, (kt + 1) & 31);
    asm volatile("s_waitcnt vmcnt(2)" ::: "memory");  // tile-kt K retired
    __builtin_amdgcn_s_barrier();
    f32x4 s[4] = {};
#pragma unroll
    for (int j = 0; j < 4; ++j) {
      bf16x8 k0 = *(const bf16x8*)(&Ks[cur][(j * 16 + fr) * 64 + c0]);
      bf16x8 k1 = *(const bf16x8*)(&Ks[cur][(j * 16 + fr) * 64 + c1]);
      s[j] = __builtin_amdgcn_mfma_f32_16x16x32_bf16(k0, qa0, s[j], 0, 0, 0);
      s[j] = __builtin_amdgcn_mfma_f32_16x16x32_bf16(k1, qa1, s[j], 0, 0, 0);
    }
    unsigned mlo = (unsigned)mw, mhi = (unsigned)(mw >> 32);
#pragma unroll
    for (int j = 0; j < 4; ++j) {
      unsigned mj = ((j & 2) ? mhi : mlo) >> ((j & 1) * 16 + msh);
#pragma unroll
      for (int r = 0; r < 4; ++r) rsum += exp2f((mj & (1u << r)) ? ninf : s[j][r]);
    }
    asm volatile("s_waitcnt lgkmcnt(0)" ::: "memory");
    __builtin_amdgcn_s_barrier();
    cur ^= 1;
  }
  rsum += __shfl_xor(rsum, 16);
  rsum += __shfl_xor(rsum, 32);
  const float rs = 1.0f / rsum;

  // ================= pass 2: normalize, write attn (coalesced), PV =================
  // Ks[cur] holds tile 0 (wrap stage of pass-1 iter 31, not yet awaited).
  STAGE_V(cur, 0);
  asm volatile("s_waitcnt vmcnt(0)" ::: "memory");  // one-time drain: K0 + V0
  __builtin_amdgcn_s_barrier();
  f32x4 o[4] = {};
  const int orow = lane >> 4, ocol = (lane & 15) * 4;
  float* abase = attn_out + ((size_t)bh * 2048 + q0 + wave * 16) * 2048;

  for (int kt = 0; kt < 32; ++kt) {
    unsigned long long mw = mrow[kt];
    STAGE_K(cur ^ 1, (kt + 1) & 31);
    STAGE_V(cur ^ 1, (kt + 1) & 31);
    asm volatile("s_waitcnt vmcnt(7)" ::: "memory");  // tile-kt K+V retired
    __builtin_amdgcn_s_barrier();
    f32x4 s[4] = {};
#pragma unroll
    for (int j = 0; j < 4; ++j) {
      bf16x8 k0 = *(const bf16x8*)(&Ks[cur][(j * 16 + fr) * 64 + c0]);
      bf16x8 k1 = *(const bf16x8*)(&Ks[cur][(j * 16 + fr) * 64 + c1]);
      s[j] = __builtin_amdgcn_mfma_f32_16x16x32_bf16(k0, qa0, s[j], 0, 0, 0);
      s[j] = __builtin_amdgcn_mfma_f32_16x16x32_bf16(k1, qa1, s[j], 0, 0, 0);
    }
    unsigned mlo = (unsigned)mw, mhi = (unsigned)(mw >> 32);
    unsigned pk[4][2];
#pragma unroll
    for (int j = 0; j < 4; ++j) {
      unsigned mj = ((j & 2) ? mhi : mlo) >> ((j & 1) * 16 + msh);
      float e0 = exp2f((mj & 1u) ? ninf : s[j][0]) * rs;
      float e1 = exp2f((mj & 2u) ? ninf : s[j][1]) * rs;
      float e2 = exp2f((mj & 4u) ? ninf : s[j][2]) * rs;
      float e3 = exp2f((mj & 8u) ? ninf : s[j][3]) * rs;
      f32x4 ev;
      ev[0] = e0; ev[1] = e1; ev[2] = e2; ev[3] = e3;
      *(f32x4*)(&Os[wave][fr * 65 + j * 16 + fg * 4]) = ev;  // LDS bounce
      asm("v_cvt_pk_bf16_f32 %0, %1, %2" : "=v"(pk[j][0]) : "v"(e0), "v"(e1));
      asm("v_cvt_pk_bf16_f32 %0, %1, %2" : "=v"(pk[j][1]) : "v"(e2), "v"(e3));
    }
    // in-register P redistribution (verified round 8): swap32 then swap16 of
    // (w[2ks][p], w[2ks+1][p]) yields the two A-operand words directly.
    unsigned x0 = pk[0][0], y0 = pk[1][0], x1 = pk[0][1], y1 = pk[1][1];
    unsigned x2 = pk[2][0], y2 = pk[3][0], x3 = pk[2][1], y3 = pk[3][1];
    asm("v_permlane32_swap_b32 %0, %1" : "+v"(x0), "+v"(y0));
    asm("v_permlane16_swap_b32 %0, %1" : "+v"(x0), "+v"(y0));
    asm("v_permlane32_swap_b32 %0, %1" : "+v"(x1), "+v"(y1));
    asm("v_permlane16_swap_b32 %0, %1" : "+v"(x1), "+v"(y1));
    asm("v_permlane32_swap_b32 %0, %1" : "+v"(x2), "+v"(y2));
    asm("v_permlane16_swap_b32 %0, %1" : "+v"(x2), "+v"(y2));
    asm("v_permlane32_swap_b32 %0, %1" : "+v"(x3), "+v"(y3));
    asm("v_permlane16_swap_b32 %0, %1" : "+v"(x3), "+v"(y3));
    u32x4 t0, t1;
    t0[0] = x0; t0[1] = x1; t0[2] = y0; t0[3] = y1;
    t1[0] = x2; t1[1] = x3; t1[2] = y2; t1[3] = y3;
    bf16x8 pa0 = __builtin_bit_cast(bf16x8, t0);
    bf16x8 pa1 = __builtin_bit_cast(bf16x8, t1);
#pragma unroll
    for (int ct = 0; ct < 4; ++ct) {
      bf16x8 v0 = *(const bf16x8*)(&Vs[cur][(ct * 16 + fr) * 64 + c0]);
      bf16x8 v1 = *(const bf16x8*)(&Vs[cur][(ct * 16 + fr) * 64 + c1]);
      o[ct] = __builtin_amdgcn_mfma_f32_16x16x32_bf16(pa0, v0, o[ct], 0, 0, 0);
      o[ct] = __builtin_amdgcn_mfma_f32_16x16x32_bf16(pa1, v1, o[ct], 0, 0, 0);
    }
    // coalesced write-out: instr i writes rows {orow+4i}, lanes 0-15 = one full
    // 256B row segment (4 segments/instr vs 16x64B before)
#pragma unroll
    for (int i = 0; i < 4; ++i) {
      f32x4 ov = *(const f32x4*)(&Os[wave][(orow + 4 * i) * 65 + ocol]);
      __builtin_nontemporal_store(
          ov, (f32x4*)(abase + (size_t)(orow + 4 * i) * 2048 + kt * 64 + ocol));
    }
    asm volatile("s_waitcnt lgkmcnt(0)" ::: "memory");
    __builtin_amdgcn_s_barrier();
    cur ^= 1;
  }
#pragma unroll
  for (int ct = 0; ct < 4; ++ct)
#pragma unroll
    for (int r = 0; r < 4; ++r)
      ctx[(size_t)(b * 2048 + q0 + wave * 16 + fg * 4 + r) * 1024 + h * 64 + ct * 16 + fr] =
          f2bf(o[ct][r]);
#undef STAGE_K
#undef STAGE_V
}

// ---------------- LayerNorm (residual already added by gemm_fc) ----------------
__global__ __launch_bounds__(256) void ln_kernel(const float* __restrict__ resl,
                                                 float* __restrict__ out) {
  __shared__ float red[8];
  const int row = blockIdx.x, tid = threadIdx.x;
  const int wave = tid >> 6, lane = tid & 63;
  float4 xv = ((const float4*)(resl + (size_t)row * 1024))[tid];
  float v0 = xv.x, v1 = xv.y, v2 = xv.z, v3 = xv.w;
  float s = v0 + v1 + v2 + v3;
  float s2 = v0 * v0 + v1 * v1 + v2 * v2 + v3 * v3;
#pragma unroll
  for (int off = 1; off < 64; off <<= 1) {
    s += __shfl_xor(s, off);
    s2 += __shfl_xor(s2, off);
  }
  if (lane == 0) { red[wave] = s; red[4 + wave] = s2; }
  __syncthreads();
  s = red[0] + red[1] + red[2] + red[3];
  s2 = red[4] + red[5] + red[6] + red[7];
  const float mu = s * (1.0f / 1024.0f);
  const float var = s2 * (1.0f / 1024.0f) - mu * mu;
  const float inv = rsqrtf(var + 1e-5f);
  float4 ov;
  ov.x = (v0 - mu) * inv;
  ov.y = (v1 - mu) * inv;
  ov.z = (v2 - mu) * inv;
  ov.w = (v3 - mu) * inv;
  ((float4*)(out + (size_t)row * 1024))[tid] = ov;
}

extern "C" void kernel_launch(void* const* d_in, const int* in_sizes, int n_in, void* d_out,
                              int out_size, void* d_ws, size_t ws_size, hipStream_t stream) {
  const float* inQ = (const float*)d_in[0];
  const float* inK = (const float*)d_in[1];
  const float* inV = (const float*)d_in[2];
  const int* mask = (const int*)d_in[3];
  const float* WQ = (const float*)d_in[4];
  const float* WK = (const float*)d_in[5];
  const float* WV = (const float*)d_in[6];
  const float* WF = (const float*)d_in[7];
  float* res = (float*)d_out;
  float* attn = res + (size_t)8192 * 1024;

  char* w = (char*)d_ws;
  unsigned short* inQb = (unsigned short*)w; w += (size_t)16777216;   // 3x contiguous
  unsigned short* inKb = (unsigned short*)w; w += (size_t)16777216;
  unsigned short* inVb = (unsigned short*)w; w += (size_t)16777216;
  unsigned short* WQt = (unsigned short*)w; w += (size_t)2097152;     // 4x contiguous
  unsigned short* WKt = (unsigned short*)w; w += (size_t)2097152;
  unsigned short* WVt = (unsigned short*)w; w += (size_t)2097152;
  unsigned short* WFt = (unsigned short*)w; w += (size_t)2097152;
  unsigned short* Qp  = (unsigned short*)w; w += (size_t)16777216;    // 3x contiguous
  unsigned short* Kp  = (unsigned short*)w; w += (size_t)16777216;
  unsigned short* Vp  = (unsigned short*)w; w += (size_t)16777216;
  unsigned short* Vtb = (unsigned short*)w; w += (size_t)16777216;
  unsigned short* ctx = (unsigned short*)w; w += (size_t)16777216;
  float* resl = (float*)w; w += (size_t)33554432;
  // mask bitwords reuse inQb's space (dead after the QKV projection GEMM)
  unsigned long long* mbits = (unsigned long long*)inQb;
  (void)inKb; (void)inVb; (void)WKt; (void)WVt; (void)Kp; (void)Vp;

  cvt3_kernel<<<24576, 256, 0, stream>>>(inQ, inK, inV, inQb);
  wtrans4_kernel<<<dim3(32, 32, 4), dim3(32, 8), 0, stream>>>(WQ, WK, WV, WF, WQt);
  gemm_qkv<<<1536, 256, 0, stream>>>(inQb, WQt, Qp, Vtb);
  maskbits_kernel<<<65536, 256, 0, stream>>>(mask, mbits);
  attn_kernel<<<1024, 512, 0, stream>>>(Qp, Kp, Vtb, mbits, attn, ctx);
  gemm_fc<<<512, 256, 0, stream>>>(ctx, WFt, resl, inQ);
  ln_kernel<<<8192, 256, 0, stream>>>(resl, res);
}